// Round 1
// baseline (571.727 us; speedup 1.0000x reference)
//
#include <hip/hip_runtime.h>

typedef unsigned short u16;
typedef unsigned int u32;
typedef __attribute__((ext_vector_type(8))) short short8;
typedef __attribute__((ext_vector_type(4))) float f32x4;

// Bit-exact emulation of the reference's round-to-e4m3 on a pre-scaled value,
// returned as bf16 bits (exact: quantized values have <=4 significand bits).
// e = clip(floor(log2(max(|v|,2^-9))), -7, 8); q = round(|v|/2^e*8)/8*2^e
// Magic-add: s = 2^(e+20) => RNE to grid 2^(e-3); clamp s >= 2^13 realizes e>=-7.
__device__ __forceinline__ u16 quant_bf16(float v, float scale) {
  float sc = v * scale;
  sc = fminf(448.0f, fmaxf(-448.0f, sc));
  u32 b = __float_as_uint(sc);
  u32 sb = (b & 0x7f800000u) + 0x0A000000u;
  sb = sb < 0x46000000u ? 0x46000000u : sb;
  float mg = __uint_as_float(sb);
  float q = (fabsf(sc) + mg) - mg;
  u32 qb = __float_as_uint(q) | (b & 0x80000000u);
  return (u16)(qb >> 16);
}

__device__ __forceinline__ float block_max(float m) {
#pragma unroll
  for (int off = 32; off > 0; off >>= 1)
    m = fmaxf(m, __shfl_down(m, off, 64));
  __shared__ float sm[4];
  int wv = threadIdx.x >> 6;
  if ((threadIdx.x & 63) == 0) sm[wv] = m;
  __syncthreads();
  float r = fmaxf(fmaxf(sm[0], sm[1]), fmaxf(sm[2], sm[3]));
  __syncthreads();
  return r;
}

#define XBLOCKS 2048
#define WBLOCKS 64

// blocks [0,2048): amax partials over x; [2048,2112): over w. No atomics, no init.
__global__ void amax2_kernel(const float4* __restrict__ x, int nx4,
                             const float4* __restrict__ w, int nw4,
                             float* __restrict__ px, float* __restrict__ pw) {
  int bid = blockIdx.x;
  const float4* p;
  int n4, b, nb;
  float* dst;
  if (bid < XBLOCKS) { p = x; n4 = nx4; dst = px; b = bid; nb = XBLOCKS; }
  else { p = w; n4 = nw4; dst = pw; b = bid - XBLOCKS; nb = WBLOCKS; }
  float m = 0.0f;
  int stride = nb * 256;
  for (int i = b * 256 + threadIdx.x; i < n4; i += stride) {
    float4 v = p[i];
    m = fmaxf(m, fmaxf(fmaxf(fabsf(v.x), fabsf(v.y)), fmaxf(fabsf(v.z), fabsf(v.w))));
  }
  m = block_max(m);
  if (threadIdx.x == 0) dst[b] = m;
}

__global__ void scales_kernel(const float* __restrict__ px, const float* __restrict__ pw,
                              float* __restrict__ wsf) {
  int tid = threadIdx.x;
  float mx = 0.0f;
  for (int i = tid; i < XBLOCKS; i += 256) mx = fmaxf(mx, px[i]);
  mx = block_max(mx);
  float mw = tid < WBLOCKS ? pw[tid] : 0.0f;
  mw = block_max(mw);
  if (tid == 0) {
    float sx = mx > 0.0f ? 448.0f / mx * 0.9f : 1.0f;  // exact op order of reference
    float sw = mw > 0.0f ? 448.0f / mw * 0.9f : 1.0f;
    wsf[2] = sx;
    wsf[3] = sw;
    wsf[4] = 1.0f / (sx * sw);
  }
}

// Quantize w into a TILED layout: wq[kc][n][8] with kc = k>>3 (8-col chunk), i.e.
// wq[kc*4096 + n*8 + (k&7)] = q(w[n][k]). Makes each GEMM B-stage chunk a 4-KB
// contiguous global region (perfect global_load_lds coalescing) and gives
// conflict-free ds_read_b128 fragment reads (contiguous 256 B per 16-lane quad).
__global__ void quant_w_kernel(const float* __restrict__ w, u16* __restrict__ wq,
                               const float* __restrict__ wsf) {
  const float sw = wsf[3];
  const int id = blockIdx.x * blockDim.x + threadIdx.x;  // 32768 = 64 kc * 512 n
  const int kc = id >> 9;
  const int n = id & 511;
  const float4* src = (const float4*)(w + (size_t)n * 512 + kc * 8);
  const float4 a = src[0];
  const float4 b = src[1];
  uint4 r;
  r.x = (u32)quant_bf16(a.x, sw) | ((u32)quant_bf16(a.y, sw) << 16);
  r.y = (u32)quant_bf16(a.z, sw) | ((u32)quant_bf16(a.w, sw) << 16);
  r.z = (u32)quant_bf16(b.x, sw) | ((u32)quant_bf16(b.y, sw) << 16);
  r.w = (u32)quant_bf16(b.z, sw) | ((u32)quant_bf16(b.w, sw) << 16);
  *(uint4*)&wq[(size_t)kc * 4096 + n * 8] = r;
}

// C = (q(x) @ q(w)^T + bias) * inv.  BM=128, BN=256, BK=32, 256 thr (4 waves 2x2;
// wave computes 64x128 = 4x8 16x16 tiles).
// LDS tiles in quad-chunk layout [q][row][8] (q = 8-col chunk of BK=32):
//   - fragment ds_read_b128: each 16-lane quad reads a contiguous 256 B region
//     -> 2 dwords/bank = conflict-free (was 8-way at the old 64-B row stride).
// Double-buffered (48 KB) with one barrier/iter:
//   issue next x float4 loads -> issue next w global_load_lds -> MFMA current
//   -> quant+ds_write next A (T14 issue-early/write-late) -> __syncthreads.
// Grid: 1-D swizzled so the 2 blocks sharing an x row-tile have linear ids differing
// by 8 -> same XCD under round-robin dispatch -> 2nd x read hits that XCD's L2.
__global__ void __launch_bounds__(256, 2) gemm_kernel(const float* __restrict__ x,
                                                      const u16* __restrict__ wq,
                                                      const float* __restrict__ bias,
                                                      float* __restrict__ out,
                                                      const float* __restrict__ wsf) {
  __shared__ u16 As[2 * 4096];   // [bu][q][128][8] bf16, 16 KB
  __shared__ u16 Bs[2 * 8192];   // [bu][q][256][8] bf16, 32 KB
  const int tid = threadIdx.x;
  const int lane = tid & 63;
  const int wv = tid >> 6;
  const int quad = lane >> 4;
  const int lr = lane & 15;

  const int lin = blockIdx.x;
  const int xcd = lin & 7;
  const int jn = (lin >> 3) & 1;
  const int grp = lin >> 4;
  const int m0 = (grp * 8 + xcd) * 128;
  const int n0 = jn * 256;

  const float sx = wsf[2];
  const float inv = wsf[4];
  const int wm = (wv >> 1) * 64;
  const int wn = (wv & 1) * 128;
  const int xrow = tid >> 3;       // 0..31
  const int xcol = (tid & 7) * 4;  // 0..28 step 4
  const int aq = xcol >> 3;        // quad-chunk this thread's float4 belongs to
  const int aoff = xcol & 7;       // 0 or 4

  f32x4 acc[4][8] = {};
  float4 xr[4];

  // ---- stage w tile for k-step kt into buffer bu (wave wv owns chunk q=wv) ----
  auto stageB = [&](int bu, int kt) {
#pragma unroll
    for (int i = 0; i < 4; ++i) {
      const u16* gp = wq + (size_t)(kt * 4 + wv) * 4096 + (size_t)n0 * 8 + (i * 64 + lane) * 8;
      u16* lp = &Bs[bu * 8192 + wv * 2048 + (i * 64 + lane) * 8];
      __builtin_amdgcn_global_load_lds((const __attribute__((address_space(1))) u32*)gp,
                                       (__attribute__((address_space(3))) u32*)lp, 16, 0, 0);
    }
  };
  // ---- issue x fp32 loads for k-step kt into registers ----
  auto loadX = [&](int kt) {
#pragma unroll
    for (int s = 0; s < 4; ++s) {
      const int r = s * 32 + xrow;
      xr[s] = *(const float4*)(x + (size_t)(m0 + r) * 512 + kt * 32 + xcol);
    }
  };
  // ---- quantize + write registers into A tile (tiled layout) ----
  auto writeA = [&](int bu) {
#pragma unroll
    for (int s = 0; s < 4; ++s) {
      const int r = s * 32 + xrow;
      uint2 pk;
      pk.x = (u32)quant_bf16(xr[s].x, sx) | ((u32)quant_bf16(xr[s].y, sx) << 16);
      pk.y = (u32)quant_bf16(xr[s].z, sx) | ((u32)quant_bf16(xr[s].w, sx) << 16);
      *(uint2*)&As[bu * 4096 + aq * 1024 + r * 8 + aoff] = pk;
    }
  };

  // prologue: tile 0 into buffer 0
  stageB(0, 0);
  loadX(0);
  writeA(0);
  __syncthreads();

  for (int kt = 0; kt < 16; ++kt) {
    const int cur = kt & 1;
    if (kt < 15) {
      loadX(kt + 1);           // x loads in flight across the MFMA block
      stageB(cur ^ 1, kt + 1); // w direct-to-LDS in flight across the MFMA block
    }
    short8 af[4], bf[8];
#pragma unroll
    for (int mi = 0; mi < 4; ++mi)
      af[mi] = *(const short8*)&As[cur * 4096 + quad * 1024 + (wm + mi * 16 + lr) * 8];
#pragma unroll
    for (int ni = 0; ni < 8; ++ni)
      bf[ni] = *(const short8*)&Bs[cur * 8192 + quad * 2048 + (wn + ni * 16 + lr) * 8];
#pragma unroll
    for (int mi = 0; mi < 4; ++mi)
#pragma unroll
      for (int ni = 0; ni < 8; ++ni)
        acc[mi][ni] = __builtin_amdgcn_mfma_f32_16x16x32_bf16(af[mi], bf[ni], acc[mi][ni], 0, 0, 0);
    if (kt < 15) writeA(cur ^ 1);  // quant after MFMA: loads have landed by now
    __syncthreads();               // drains vmcnt (w stage) + lgkmcnt (A writes)
  }

  // ---- epilogue: out = (acc + bias) * inv ; C layout col=lane&15, row=quad*4+reg ----
  float bn[8];
#pragma unroll
  for (int ni = 0; ni < 8; ++ni) bn[ni] = bias[n0 + wn + ni * 16 + lr];
#pragma unroll
  for (int mi = 0; mi < 4; ++mi) {
    const int gr = m0 + wm + mi * 16 + quad * 4;
#pragma unroll
    for (int ni = 0; ni < 8; ++ni) {
      const int gc = n0 + wn + ni * 16 + lr;
#pragma unroll
      for (int j = 0; j < 4; ++j)
        out[(size_t)(gr + j) * 512 + gc] = (acc[mi][ni][j] + bn[ni]) * inv;
    }
  }
}

extern "C" void kernel_launch(void* const* d_in, const int* in_sizes, int n_in,
                              void* d_out, int out_size, void* d_ws, size_t ws_size,
                              hipStream_t stream) {
  const float* x = (const float*)d_in[0];
  const float* w = (const float*)d_in[1];
  const float* bias = (const float*)d_in[2];
  float* out = (float*)d_out;

  const int K = 512, N = 512;
  const int M = in_sizes[0] / K;  // 131072

  float* ws_f = (float*)d_ws;                  // [0..16) scalars
  float* px = ws_f + 16;                       // 2048 x-partials
  float* pw = ws_f + 16 + XBLOCKS;             // 64 w-partials
  u16* wq = (u16*)((char*)d_ws + 16384);       // 512 KB bf16 quantized weight (tiled)

  hipLaunchKernelGGL(amax2_kernel, dim3(XBLOCKS + WBLOCKS), dim3(256), 0, stream,
                     (const float4*)x, (M * K) / 4, (const float4*)w, (N * K) / 4, px, pw);
  hipLaunchKernelGGL(scales_kernel, dim3(1), dim3(256), 0, stream, px, pw, ws_f);
  hipLaunchKernelGGL(quant_w_kernel, dim3((N * K / 8) / 256), dim3(256), 0, stream,
                     w, wq, ws_f);
  hipLaunchKernelGGL(gemm_kernel, dim3((M / 128) * 2), dim3(256), 0, stream,
                     x, wq, bias, out, ws_f);
}

// Round 3
// 542.456 us; speedup vs baseline: 1.0540x; 1.0540x over previous
//
#include <hip/hip_runtime.h>

typedef unsigned short u16;
typedef unsigned int u32;
typedef unsigned char u8;
typedef __attribute__((ext_vector_type(4))) float f32x4;

// Clamp two floats to +-448 and pack as OCP e4m3fn into half of a u32 via the
// HW converter (RNE, matches reference's emulated round-to-e4m3; the 2^-10
// sub-denormal grid differs -- bounded ~7e-7 in the output, negligible).
// HI selector must be a compile-time constant for the builtin.
template <bool HI>
__device__ __forceinline__ u32 q2fp8(float a, float b, u32 old, float s) {
  a = fminf(448.0f, fmaxf(-448.0f, a * s));
  b = fminf(448.0f, fmaxf(-448.0f, b * s));
  return (u32)__builtin_amdgcn_cvt_pk_fp8_f32(a, b, (int)old, HI);
}

__device__ __forceinline__ float block_max(float m) {
#pragma unroll
  for (int off = 32; off > 0; off >>= 1)
    m = fmaxf(m, __shfl_down(m, off, 64));
  __shared__ float sm[4];
  int wv = threadIdx.x >> 6;
  if ((threadIdx.x & 63) == 0) sm[wv] = m;
  __syncthreads();
  float r = fmaxf(fmaxf(sm[0], sm[1]), fmaxf(sm[2], sm[3]));
  __syncthreads();
  return r;
}

#define XBLOCKS 2048
#define WBLOCKS 64

// blocks [0,2048): amax partials over x; [2048,2112): over w. No atomics, no init.
__global__ void amax2_kernel(const float4* __restrict__ x, int nx4,
                             const float4* __restrict__ w, int nw4,
                             float* __restrict__ px, float* __restrict__ pw) {
  int bid = blockIdx.x;
  const float4* p;
  int n4, b, nb;
  float* dst;
  if (bid < XBLOCKS) { p = x; n4 = nx4; dst = px; b = bid; nb = XBLOCKS; }
  else { p = w; n4 = nw4; dst = pw; b = bid - XBLOCKS; nb = WBLOCKS; }
  float m = 0.0f;
  int stride = nb * 256;
  for (int i = b * 256 + threadIdx.x; i < n4; i += stride) {
    float4 v = p[i];
    m = fmaxf(m, fmaxf(fmaxf(fabsf(v.x), fabsf(v.y)), fmaxf(fabsf(v.z), fabsf(v.w))));
  }
  m = block_max(m);
  if (threadIdx.x == 0) dst[b] = m;
}

__global__ void scales_kernel(const float* __restrict__ px, const float* __restrict__ pw,
                              float* __restrict__ wsf) {
  int tid = threadIdx.x;
  float mx = 0.0f;
  for (int i = tid; i < XBLOCKS; i += 256) mx = fmaxf(mx, px[i]);
  mx = block_max(mx);
  float mw = tid < WBLOCKS ? pw[tid] : 0.0f;
  mw = block_max(mw);
  if (tid == 0) {
    float sx = mx > 0.0f ? 448.0f / mx * 0.9f : 1.0f;  // exact op order of reference
    float sw = mw > 0.0f ? 448.0f / mw * 0.9f : 1.0f;
    wsf[2] = sx;
    wsf[3] = sw;
    wsf[4] = 1.0f / (sx * sw);
  }
}

// Quantize w to fp8 e4m3 in a TILED layout: wq[kc][n][8] with kc = k>>3, i.e.
// wq[kc*4096 + n*8 + (k&7)] = q(w[n][k]). Each GEMM B-stage chunk is a contiguous
// global region (perfect global_load_lds coalescing) and fragment ds_read_b64
// reads are at minimum bank aliasing.
__global__ void quant_w_kernel(const float* __restrict__ w, u8* __restrict__ wq,
                               const float* __restrict__ wsf) {
  const float sw = wsf[3];
  const int id = blockIdx.x * blockDim.x + threadIdx.x;  // 32768 = 64 kc * 512 n
  const int kc = id >> 9;
  const int n = id & 511;
  const float4* src = (const float4*)(w + (size_t)n * 512 + kc * 8);
  const float4 a = src[0];
  const float4 b = src[1];
  uint2 r;
  r.x = q2fp8<false>(a.x, a.y, 0u, sw);
  r.x = q2fp8<true>(a.z, a.w, r.x, sw);
  r.y = q2fp8<false>(b.x, b.y, 0u, sw);
  r.y = q2fp8<true>(b.z, b.w, r.y, sw);
  *(uint2*)&wq[(size_t)kc * 4096 + n * 8] = r;
}

// C = (q(x) @ q(w)^T + bias) * inv, fp8 MFMA.  BM=128, BN=256, BK=32, 512 thr
// (8 waves 2x4; wave computes 64x64 = 4x4 16x16 tiles, acc = 64 VGPR).
// LDS in quad-chunk layout [q][row][8] fp8 (q = 8-col chunk of BK=32): fragment
// ds_read_b64 per quad reads contiguous 128 B -> minimum bank aliasing.
// Double-buffered (24 KB) with one barrier/iter: issue next x float4 loads ->
// issue next w global_load_lds -> MFMA current -> cvt_pk_fp8 + ds_write next A.
// __launch_bounds__(512,4): 4 waves/EU = 2 blocks/CU (50% occ), two independent
// blocks cover each other's barrier-drain stalls.
// Grid swizzle: the 2 blocks sharing an x row-tile have linear ids differing by
// 8 -> same XCD under round-robin dispatch -> 2nd x read hits that XCD's L2.
__global__ void __launch_bounds__(512, 4) gemm_kernel(const float* __restrict__ x,
                                                      const u8* __restrict__ wq,
                                                      const float* __restrict__ bias,
                                                      float* __restrict__ out,
                                                      const float* __restrict__ wsf) {
  __shared__ __align__(16) u8 As[2 * 4096];   // [bu][q][128][8] fp8, 8 KB
  __shared__ __align__(16) u8 Bs[2 * 8192];   // [bu][q][256][8] fp8, 16 KB
  const int tid = threadIdx.x;
  const int lane = tid & 63;
  const int wv = tid >> 6;          // 0..7
  const int quad = lane >> 4;
  const int lr = lane & 15;

  const int lin = blockIdx.x;
  const int xcd = lin & 7;
  const int jn = (lin >> 3) & 1;
  const int grp = lin >> 4;
  const int m0 = (grp * 8 + xcd) * 128;
  const int n0 = jn * 256;

  const float sx = wsf[2];
  const float inv = wsf[4];
  const int wm = (wv >> 2) * 64;    // wave row: 0 or 64
  const int wn = (wv & 3) * 64;     // wave col: 0,64,128,192
  const int xrow = tid >> 2;        // 0..127
  const int xcol = (tid & 3) * 8;   // 0,8,16,24
  const int aq = tid & 3;           // A quad-chunk this thread fills

  f32x4 acc[4][4] = {};
  float4 xr0, xr1;

  // ---- stage w tile for k-step kt into buffer bu (wave wv -> chunk wv>>1, half wv&1) ----
  auto stageB = [&](int bu, int kt) {
    const int c = wv >> 1;
    const int h = wv & 1;
    const u8* gp = wq + (size_t)(kt * 4 + c) * 4096 + (size_t)n0 * 8 + h * 1024 + lane * 16;
    u8* lp = &Bs[bu * 8192 + c * 2048 + h * 1024 + lane * 16];
    __builtin_amdgcn_global_load_lds((const __attribute__((address_space(1))) u32*)gp,
                                     (__attribute__((address_space(3))) u32*)lp, 16, 0, 0);
  };
  // ---- issue x fp32 loads for k-step kt into registers ----
  auto loadX = [&](int kt) {
    const float* p = x + (size_t)(m0 + xrow) * 512 + kt * 32 + xcol;
    xr0 = *(const float4*)p;
    xr1 = *(const float4*)(p + 4);
  };
  // ---- quantize (HW cvt) + write registers into A tile (tiled layout) ----
  auto writeA = [&](int bu) {
    uint2 pk;
    pk.x = q2fp8<false>(xr0.x, xr0.y, 0u, sx);
    pk.x = q2fp8<true>(xr0.z, xr0.w, pk.x, sx);
    pk.y = q2fp8<false>(xr1.x, xr1.y, 0u, sx);
    pk.y = q2fp8<true>(xr1.z, xr1.w, pk.y, sx);
    *(uint2*)&As[bu * 4096 + aq * 1024 + xrow * 8] = pk;
  };

  // prologue: tile 0 into buffer 0
  stageB(0, 0);
  loadX(0);
  writeA(0);
  __syncthreads();

  for (int kt = 0; kt < 16; ++kt) {
    const int cur = kt & 1;
    if (kt < 15) {
      loadX(kt + 1);            // x loads in flight across the MFMA block
      stageB(cur ^ 1, kt + 1);  // w direct-to-LDS in flight across the MFMA block
    }
    long af[4], bf[4];
#pragma unroll
    for (int mi = 0; mi < 4; ++mi)
      af[mi] = *(const long*)&As[cur * 4096 + quad * 1024 + (wm + mi * 16 + lr) * 8];
#pragma unroll
    for (int ni = 0; ni < 4; ++ni)
      bf[ni] = *(const long*)&Bs[cur * 8192 + quad * 2048 + (wn + ni * 16 + lr) * 8];
#pragma unroll
    for (int mi = 0; mi < 4; ++mi)
#pragma unroll
      for (int ni = 0; ni < 4; ++ni)
        acc[mi][ni] = __builtin_amdgcn_mfma_f32_16x16x32_fp8_fp8(af[mi], bf[ni], acc[mi][ni], 0, 0, 0);
    if (kt < 15) writeA(cur ^ 1);  // cvt after MFMA: loads have landed by now
    __syncthreads();               // drains vmcnt (w stage) + lgkmcnt (A writes)
  }

  // ---- epilogue: out = (acc + bias) * inv ; C layout col=lane&15, row=quad*4+reg ----
  float bn[4];
#pragma unroll
  for (int ni = 0; ni < 4; ++ni) bn[ni] = bias[n0 + wn + ni * 16 + lr];
#pragma unroll
  for (int mi = 0; mi < 4; ++mi) {
    const int gr = m0 + wm + mi * 16 + quad * 4;
#pragma unroll
    for (int ni = 0; ni < 4; ++ni) {
      const int gc = n0 + wn + ni * 16 + lr;
#pragma unroll
      for (int j = 0; j < 4; ++j)
        out[(size_t)(gr + j) * 512 + gc] = (acc[mi][ni][j] + bn[ni]) * inv;
    }
  }
}

extern "C" void kernel_launch(void* const* d_in, const int* in_sizes, int n_in,
                              void* d_out, int out_size, void* d_ws, size_t ws_size,
                              hipStream_t stream) {
  const float* x = (const float*)d_in[0];
  const float* w = (const float*)d_in[1];
  const float* bias = (const float*)d_in[2];
  float* out = (float*)d_out;

  const int K = 512, N = 512;
  const int M = in_sizes[0] / K;  // 131072

  float* ws_f = (float*)d_ws;                  // [0..16) scalars
  float* px = ws_f + 16;                       // 2048 x-partials
  float* pw = ws_f + 16 + XBLOCKS;             // 64 w-partials
  u8* wq = (u8*)((char*)d_ws + 16384);         // 256 KB fp8 quantized weight (tiled)

  hipLaunchKernelGGL(amax2_kernel, dim3(XBLOCKS + WBLOCKS), dim3(256), 0, stream,
                     (const float4*)x, (M * K) / 4, (const float4*)w, (N * K) / 4, px, pw);
  hipLaunchKernelGGL(scales_kernel, dim3(1), dim3(256), 0, stream, px, pw, ws_f);
  hipLaunchKernelGGL(quant_w_kernel, dim3((N * K / 8) / 256), dim3(256), 0, stream,
                     w, wq, ws_f);
  hipLaunchKernelGGL(gemm_kernel, dim3((M / 128) * 2), dim3(512), 0, stream,
                     x, wq, bias, out, ws_f);
}

// Round 4
// 525.079 us; speedup vs baseline: 1.0888x; 1.0331x over previous
//
#include <hip/hip_runtime.h>

typedef unsigned short u16;
typedef unsigned int u32;
typedef unsigned char u8;
typedef __attribute__((ext_vector_type(4))) float f32x4;

// Clamp two floats to +-448 and pack as OCP e4m3fn into half of a u32 via the
// HW converter (RNE). HI selector must be a compile-time constant.
template <bool HI>
__device__ __forceinline__ u32 q2fp8(float a, float b, u32 old, float s) {
  a = fminf(448.0f, fmaxf(-448.0f, a * s));
  b = fminf(448.0f, fmaxf(-448.0f, b * s));
  return (u32)__builtin_amdgcn_cvt_pk_fp8_f32(a, b, (int)old, HI);
}

__device__ __forceinline__ float block_max(float m) {
#pragma unroll
  for (int off = 32; off > 0; off >>= 1)
    m = fmaxf(m, __shfl_down(m, off, 64));
  __shared__ float sm[4];
  int wv = threadIdx.x >> 6;
  if ((threadIdx.x & 63) == 0) sm[wv] = m;
  __syncthreads();
  float r = fmaxf(fmaxf(sm[0], sm[1]), fmaxf(sm[2], sm[3]));
  __syncthreads();
  return r;
}

#define XBLOCKS 2048
#define WBLOCKS 64

// blocks [0,2048): amax partials over x; [2048,2112): over w. No atomics, no init.
__global__ void amax2_kernel(const float4* __restrict__ x, int nx4,
                             const float4* __restrict__ w, int nw4,
                             float* __restrict__ px, float* __restrict__ pw) {
  int bid = blockIdx.x;
  const float4* p;
  int n4, b, nb;
  float* dst;
  if (bid < XBLOCKS) { p = x; n4 = nx4; dst = px; b = bid; nb = XBLOCKS; }
  else { p = w; n4 = nw4; dst = pw; b = bid - XBLOCKS; nb = WBLOCKS; }
  float m = 0.0f;
  int stride = nb * 256;
  for (int i = b * 256 + threadIdx.x; i < n4; i += stride) {
    float4 v = p[i];
    m = fmaxf(m, fmaxf(fmaxf(fabsf(v.x), fabsf(v.y)), fmaxf(fabsf(v.z), fabsf(v.w))));
  }
  m = block_max(m);
  if (threadIdx.x == 0) dst[b] = m;
}

__global__ void scales_kernel(const float* __restrict__ px, const float* __restrict__ pw,
                              float* __restrict__ wsf) {
  int tid = threadIdx.x;
  float mx = 0.0f;
  for (int i = tid; i < XBLOCKS; i += 256) mx = fmaxf(mx, px[i]);
  mx = block_max(mx);
  float mw = tid < WBLOCKS ? pw[tid] : 0.0f;
  mw = block_max(mw);
  if (tid == 0) {
    float sx = mx > 0.0f ? 448.0f / mx * 0.9f : 1.0f;  // exact op order of reference
    float sw = mw > 0.0f ? 448.0f / mw * 0.9f : 1.0f;
    wsf[2] = sx;
    wsf[3] = sw;
    wsf[4] = 1.0f / (sx * sw);
  }
}

// Quantize w to fp8 e4m3 in a TILED layout: wq[kc][n][8] with kc = k>>3, i.e.
// wq[kc*4096 + n*8 + (k&7)] = q(w[n][k]). Each GEMM B-stage chunk is a contiguous
// global region (perfect global_load_lds coalescing) and fragment ds_read_b64
// reads are at minimum bank aliasing.
__global__ void quant_w_kernel(const float* __restrict__ w, u8* __restrict__ wq,
                               const float* __restrict__ wsf) {
  const float sw = wsf[3];
  const int id = blockIdx.x * blockDim.x + threadIdx.x;  // 32768 = 64 kc * 512 n
  const int kc = id >> 9;
  const int n = id & 511;
  const float4* src = (const float4*)(w + (size_t)n * 512 + kc * 8);
  const float4 a = src[0];
  const float4 b = src[1];
  uint2 r;
  r.x = q2fp8<false>(a.x, a.y, 0u, sw);
  r.x = q2fp8<true>(a.z, a.w, r.x, sw);
  r.y = q2fp8<false>(b.x, b.y, 0u, sw);
  r.y = q2fp8<true>(b.z, b.w, r.y, sw);
  *(uint2*)&wq[(size_t)kc * 4096 + n * 8] = r;
}

// C = (q(x) @ q(w)^T + bias) * inv, fp8 MFMA.  BM=128, BN=256, BK=64, 512 thr
// (8 waves 2x4; wave computes 64x64 = 4x4 16x16 tiles, acc = 64 VGPR).
// BK=64: 8 k-iterations (vs 16) -> half the barriers; 32 MFMA/wave per iter
// (~640 cyc/SIMD at 4 waves) covers the HBM latency that the barrier's implicit
// vmcnt(0) drain must wait for.
// LDS in 8-col-chunk layout [c][row][8] fp8: fragment ds_read_b64 per quad reads
// contiguous 128 B -> minimum bank aliasing. Double-buffered (48 KB).
// Per iter: issue next x float4 loads -> issue next w global_load_lds -> MFMA
// current (fragments loaded per-kk to stay <=128 VGPR) -> cvt+ds_write next A
// -> one __syncthreads.
// Grid swizzle: the 2 blocks sharing an x row-tile have linear ids differing by
// 8 -> same XCD under round-robin dispatch -> 2nd x read hits that XCD's L2.
__global__ void __launch_bounds__(512, 4) gemm_kernel(const float* __restrict__ x,
                                                      const u8* __restrict__ wq,
                                                      const float* __restrict__ bias,
                                                      float* __restrict__ out,
                                                      const float* __restrict__ wsf) {
  __shared__ __align__(16) u8 As[2 * 8192];    // [bu][c:8][128][8] fp8, 16 KB
  __shared__ __align__(16) u8 Bs[2 * 16384];   // [bu][c:8][256][8] fp8, 32 KB
  const int tid = threadIdx.x;
  const int lane = tid & 63;
  const int wv = tid >> 6;          // 0..7
  const int quad = lane >> 4;
  const int lr = lane & 15;

  const int lin = blockIdx.x;
  const int xcd = lin & 7;
  const int jn = (lin >> 3) & 1;
  const int grp = lin >> 4;
  const int m0 = (grp * 8 + xcd) * 128;
  const int n0 = jn * 256;

  const float sx = wsf[2];
  const float inv = wsf[4];
  const int wm = (wv >> 2) * 64;    // wave row: 0 or 64
  const int wn = (wv & 3) * 64;     // wave col: 0,64,128,192
  const int xrow = tid >> 2;        // 0..127
  const int xq0 = (tid & 3) * 2;    // first of 2 chunks this thread fills: 0,2,4,6

  f32x4 acc[4][4] = {};
  float4 xr[4];

  // ---- stage w tile (16 KB) for k-step kt into buffer bu; wave wv owns chunk wv ----
  auto stageB = [&](int bu, int kt) {
#pragma unroll
    for (int i = 0; i < 2; ++i) {
      const u8* gp = wq + (size_t)(kt * 8 + wv) * 4096 + (size_t)n0 * 8 + i * 1024 + lane * 16;
      u8* lp = &Bs[bu * 16384 + wv * 2048 + i * 1024 + lane * 16];
      __builtin_amdgcn_global_load_lds((const __attribute__((address_space(1))) u32*)gp,
                                       (__attribute__((address_space(3))) u32*)lp, 16, 0, 0);
    }
  };
  // ---- issue x fp32 loads (64 B/thread) for k-step kt into registers ----
  auto loadX = [&](int kt) {
    const float* p = x + (size_t)(m0 + xrow) * 512 + kt * 64 + xq0 * 8;
#pragma unroll
    for (int s = 0; s < 4; ++s) xr[s] = *(const float4*)(p + s * 4);
  };
  // ---- quantize (HW cvt) + write registers into A tile (chunk layout) ----
  auto writeA = [&](int bu) {
#pragma unroll
    for (int j = 0; j < 2; ++j) {
      uint2 pk;
      pk.x = q2fp8<false>(xr[2 * j].x, xr[2 * j].y, 0u, sx);
      pk.x = q2fp8<true>(xr[2 * j].z, xr[2 * j].w, pk.x, sx);
      pk.y = q2fp8<false>(xr[2 * j + 1].x, xr[2 * j + 1].y, 0u, sx);
      pk.y = q2fp8<true>(xr[2 * j + 1].z, xr[2 * j + 1].w, pk.y, sx);
      *(uint2*)&As[bu * 8192 + (xq0 + j) * 1024 + xrow * 8] = pk;
    }
  };

  // prologue: tile 0 into buffer 0
  stageB(0, 0);
  loadX(0);
  writeA(0);
  __syncthreads();

  for (int kt = 0; kt < 8; ++kt) {
    const int cur = kt & 1;
    if (kt < 7) {
      loadX(kt + 1);            // x loads in flight across the MFMA block
      stageB(cur ^ 1, kt + 1);  // w direct-to-LDS in flight across the MFMA block
    }
#pragma unroll
    for (int kk = 0; kk < 2; ++kk) {
      long af[4], bf[4];
#pragma unroll
      for (int mi = 0; mi < 4; ++mi)
        af[mi] = *(const long*)&As[cur * 8192 + (kk * 4 + quad) * 1024 + (wm + mi * 16 + lr) * 8];
#pragma unroll
      for (int ni = 0; ni < 4; ++ni)
        bf[ni] = *(const long*)&Bs[cur * 16384 + (kk * 4 + quad) * 2048 + (wn + ni * 16 + lr) * 8];
#pragma unroll
      for (int mi = 0; mi < 4; ++mi)
#pragma unroll
        for (int ni = 0; ni < 4; ++ni)
          acc[mi][ni] = __builtin_amdgcn_mfma_f32_16x16x32_fp8_fp8(af[mi], bf[ni], acc[mi][ni], 0, 0, 0);
    }
    if (kt < 7) writeA(cur ^ 1);  // cvt after MFMA: loads have landed by now
    __syncthreads();              // drains vmcnt (w stage) + lgkmcnt (A writes)
  }

  // ---- epilogue: out = (acc + bias) * inv ; C layout col=lane&15, row=quad*4+reg ----
  float bn[4];
#pragma unroll
  for (int ni = 0; ni < 4; ++ni) bn[ni] = bias[n0 + wn + ni * 16 + lr];
#pragma unroll
  for (int mi = 0; mi < 4; ++mi) {
    const int gr = m0 + wm + mi * 16 + quad * 4;
#pragma unroll
    for (int ni = 0; ni < 4; ++ni) {
      const int gc = n0 + wn + ni * 16 + lr;
#pragma unroll
      for (int j = 0; j < 4; ++j)
        out[(size_t)(gr + j) * 512 + gc] = (acc[mi][ni][j] + bn[ni]) * inv;
    }
  }
}

extern "C" void kernel_launch(void* const* d_in, const int* in_sizes, int n_in,
                              void* d_out, int out_size, void* d_ws, size_t ws_size,
                              hipStream_t stream) {
  const float* x = (const float*)d_in[0];
  const float* w = (const float*)d_in[1];
  const float* bias = (const float*)d_in[2];
  float* out = (float*)d_out;

  const int K = 512, N = 512;
  const int M = in_sizes[0] / K;  // 131072

  float* ws_f = (float*)d_ws;                  // [0..16) scalars
  float* px = ws_f + 16;                       // 2048 x-partials
  float* pw = ws_f + 16 + XBLOCKS;             // 64 w-partials
  u8* wq = (u8*)((char*)d_ws + 16384);         // 256 KB fp8 quantized weight (tiled)

  hipLaunchKernelGGL(amax2_kernel, dim3(XBLOCKS + WBLOCKS), dim3(256), 0, stream,
                     (const float4*)x, (M * K) / 4, (const float4*)w, (N * K) / 4, px, pw);
  hipLaunchKernelGGL(scales_kernel, dim3(1), dim3(256), 0, stream, px, pw, ws_f);
  hipLaunchKernelGGL(quant_w_kernel, dim3((N * K / 8) / 256), dim3(256), 0, stream,
                     w, wq, ws_f);
  hipLaunchKernelGGL(gemm_kernel, dim3((M / 128) * 2), dim3(512), 0, stream,
                     x, wq, bias, out, ws_f);
}

// Round 5
// 519.131 us; speedup vs baseline: 1.1013x; 1.0115x over previous
//
#include <hip/hip_runtime.h>

typedef unsigned short u16;
typedef unsigned int u32;
typedef unsigned char u8;
typedef __attribute__((ext_vector_type(4))) float f32x4;

// Clamp two floats to +-448 and pack as OCP e4m3fn into half of a u32 via the
// HW converter (RNE). HI selector must be a compile-time constant.
template <bool HI>
__device__ __forceinline__ u32 q2fp8(float a, float b, u32 old, float s) {
  a = fminf(448.0f, fmaxf(-448.0f, a * s));
  b = fminf(448.0f, fmaxf(-448.0f, b * s));
  return (u32)__builtin_amdgcn_cvt_pk_fp8_f32(a, b, (int)old, HI);
}

__device__ __forceinline__ float block_max(float m) {
#pragma unroll
  for (int off = 32; off > 0; off >>= 1)
    m = fmaxf(m, __shfl_down(m, off, 64));
  __shared__ float sm[4];
  int wv = threadIdx.x >> 6;
  if ((threadIdx.x & 63) == 0) sm[wv] = m;
  __syncthreads();
  float r = fmaxf(fmaxf(sm[0], sm[1]), fmaxf(sm[2], sm[3]));
  __syncthreads();
  return r;
}

#define XBLOCKS 2048
#define WBLOCKS 64

// blocks [0,2048): amax partials over x; [2048,2112): over w. No atomics, no init.
__global__ void amax2_kernel(const float4* __restrict__ x, int nx4,
                             const float4* __restrict__ w, int nw4,
                             float* __restrict__ px, float* __restrict__ pw) {
  int bid = blockIdx.x;
  const float4* p;
  int n4, b, nb;
  float* dst;
  if (bid < XBLOCKS) { p = x; n4 = nx4; dst = px; b = bid; nb = XBLOCKS; }
  else { p = w; n4 = nw4; dst = pw; b = bid - XBLOCKS; nb = WBLOCKS; }
  float m = 0.0f;
  int stride = nb * 256;
  for (int i = b * 256 + threadIdx.x; i < n4; i += stride) {
    float4 v = p[i];
    m = fmaxf(m, fmaxf(fmaxf(fabsf(v.x), fabsf(v.y)), fmaxf(fabsf(v.z), fabsf(v.w))));
  }
  m = block_max(m);
  if (threadIdx.x == 0) dst[b] = m;
}

__global__ void scales_kernel(const float* __restrict__ px, const float* __restrict__ pw,
                              float* __restrict__ wsf) {
  int tid = threadIdx.x;
  float mx = 0.0f;
  for (int i = tid; i < XBLOCKS; i += 256) mx = fmaxf(mx, px[i]);
  mx = block_max(mx);
  float mw = tid < WBLOCKS ? pw[tid] : 0.0f;
  mw = block_max(mw);
  if (tid == 0) {
    float sx = mx > 0.0f ? 448.0f / mx * 0.9f : 1.0f;  // exact op order of reference
    float sw = mw > 0.0f ? 448.0f / mw * 0.9f : 1.0f;
    wsf[2] = sx;
    wsf[3] = sw;
    wsf[4] = 1.0f / (sx * sw);
  }
}

// Quantize w to fp8 e4m3 in a TILED layout: wq[kc][n][8] with kc = k>>3, i.e.
// wq[kc*4096 + n*8 + (k&7)] = q(w[n][k]). Each GEMM B-stage chunk is a contiguous
// global region (perfect global_load_lds coalescing) and fragment ds_read_b64
// reads are at minimum bank aliasing.
__global__ void quant_w_kernel(const float* __restrict__ w, u8* __restrict__ wq,
                               const float* __restrict__ wsf) {
  const float sw = wsf[3];
  const int id = blockIdx.x * blockDim.x + threadIdx.x;  // 32768 = 64 kc * 512 n
  const int kc = id >> 9;
  const int n = id & 511;
  const float4* src = (const float4*)(w + (size_t)n * 512 + kc * 8);
  const float4 a = src[0];
  const float4 b = src[1];
  uint2 r;
  r.x = q2fp8<false>(a.x, a.y, 0u, sw);
  r.x = q2fp8<true>(a.z, a.w, r.x, sw);
  r.y = q2fp8<false>(b.x, b.y, 0u, sw);
  r.y = q2fp8<true>(b.z, b.w, r.y, sw);
  *(uint2*)&wq[(size_t)kc * 4096 + n * 8] = r;
}

// C = (q(x) @ q(w)^T + bias) * inv, fp8 MFMA.  BM=128, BN=256, BK=64, 512 thr
// (8 waves 2x4; wave computes 64x64 = 4x4 16x16 tiles, acc = 64 VGPR).
// T3/T4 counted-vmcnt pipeline: B staged 2 tiles ahead into a 3-deep LDS ring;
// raw s_barrier with manual lgkmcnt(0) instead of __syncthreads, so the
// just-issued global_load_lds stays IN FLIGHT across the barrier. The only hard
// vmem wait is the compiler's in-order vmcnt before writeA reads xr -- that
// wait (vmcnt(2)) also proves B(kt+1) (older) landed, never draining B(kt+2).
// Ring safety: A reused after 2 barriers, B after 3; all reads of a buffer
// complete before the barrier preceding its rewrite. Fully unrolled so ring
// indices/guards are compile-time.
// LDS 64 KB -> 2 blocks/CU; ~116 VGPR -> 4 waves/EU.
// Grid swizzle: the 2 blocks sharing an x row-tile have linear ids differing by
// 8 -> same XCD under round-robin dispatch -> 2nd x read hits that XCD's L2.
__global__ void __launch_bounds__(512, 4) gemm_kernel(const float* __restrict__ x,
                                                      const u8* __restrict__ wq,
                                                      const float* __restrict__ bias,
                                                      float* __restrict__ out,
                                                      const float* __restrict__ wsf) {
  __shared__ __align__(16) u8 As[2 * 8192];    // [bu:2][c:8][128][8] fp8, 16 KB
  __shared__ __align__(16) u8 Bs[3 * 16384];   // [bu:3][c:8][256][8] fp8, 48 KB
  const int tid = threadIdx.x;
  const int lane = tid & 63;
  const int wv = tid >> 6;          // 0..7
  const int quad = lane >> 4;
  const int lr = lane & 15;

  const int lin = blockIdx.x;
  const int xcd = lin & 7;
  const int jn = (lin >> 3) & 1;
  const int grp = lin >> 4;
  const int m0 = (grp * 8 + xcd) * 128;
  const int n0 = jn * 256;

  const float sx = wsf[2];
  const float inv = wsf[4];
  const int wm = (wv >> 2) * 64;    // wave row: 0 or 64
  const int wn = (wv & 3) * 64;     // wave col: 0,64,128,192
  const int xrow = tid >> 2;        // 0..127
  const int xq0 = (tid & 3) * 2;    // first of 2 chunks this thread fills: 0,2,4,6

  f32x4 acc[4][4] = {};
  float4 xr[4];

  // ---- stage w tile (16 KB) for k-step kt into ring buffer bu; wave wv owns chunk wv ----
  auto stageB = [&](int bu, int kt) {
#pragma unroll
    for (int i = 0; i < 2; ++i) {
      const u8* gp = wq + (size_t)(kt * 8 + wv) * 4096 + (size_t)n0 * 8 + i * 1024 + lane * 16;
      u8* lp = &Bs[bu * 16384 + wv * 2048 + i * 1024 + lane * 16];
      __builtin_amdgcn_global_load_lds((const __attribute__((address_space(1))) u32*)gp,
                                       (__attribute__((address_space(3))) u32*)lp, 16, 0, 0);
    }
  };
  // ---- issue x fp32 loads (64 B/thread) for k-step kt into registers ----
  auto loadX = [&](int kt) {
    const float* p = x + (size_t)(m0 + xrow) * 512 + kt * 64 + xq0 * 8;
#pragma unroll
    for (int s = 0; s < 4; ++s) xr[s] = *(const float4*)(p + s * 4);
  };
  // ---- quantize (HW cvt) + write registers into A tile (chunk layout) ----
  auto writeA = [&](int bu) {
#pragma unroll
    for (int j = 0; j < 2; ++j) {
      uint2 pk;
      pk.x = q2fp8<false>(xr[2 * j].x, xr[2 * j].y, 0u, sx);
      pk.x = q2fp8<true>(xr[2 * j].z, xr[2 * j].w, pk.x, sx);
      pk.y = q2fp8<false>(xr[2 * j + 1].x, xr[2 * j + 1].y, 0u, sx);
      pk.y = q2fp8<true>(xr[2 * j + 1].z, xr[2 * j + 1].w, pk.y, sx);
      *(uint2*)&As[bu * 8192 + (xq0 + j) * 1024 + xrow * 8] = pk;
    }
  };

  // ---- prologue: x(0) first (oldest), then B(0), B(1) ----
  loadX(0);
  stageB(0, 0);
  stageB(1, 1);
  writeA(0);  // compiler waits x loads (vmcnt(4)): B(0),B(1) stay in flight
  asm volatile("s_waitcnt vmcnt(2) lgkmcnt(0)" ::: "memory");  // B(0) landed; B(1) in flight
  __builtin_amdgcn_s_barrier();
  asm volatile("" ::: "memory");

#pragma unroll
  for (int kt = 0; kt < 8; ++kt) {
    const int cur3 = kt % 3;
    const int curA = kt & 1;
    if (kt < 7) loadX(kt + 1);                    // 4 loads, oldest this iter
    if (kt < 6) stageB((kt + 2) % 3, kt + 2);     // 2 loads, youngest this iter
#pragma unroll
    for (int kk = 0; kk < 2; ++kk) {
      long af[4], bf[4];
#pragma unroll
      for (int mi = 0; mi < 4; ++mi)
        af[mi] = *(const long*)&As[curA * 8192 + (kk * 4 + quad) * 1024 + (wm + mi * 16 + lr) * 8];
#pragma unroll
      for (int ni = 0; ni < 4; ++ni)
        bf[ni] = *(const long*)&Bs[cur3 * 16384 + (kk * 4 + quad) * 2048 + (wn + ni * 16 + lr) * 8];
#pragma unroll
      for (int mi = 0; mi < 4; ++mi)
#pragma unroll
        for (int ni = 0; ni < 4; ++ni)
          acc[mi][ni] = __builtin_amdgcn_mfma_f32_16x16x32_fp8_fp8(af[mi], bf[ni], acc[mi][ni], 0, 0, 0);
    }
    // writeA's xr read forces (in-order) vmcnt wait that also covers B(kt+1);
    // B(kt+2) stays in flight across the barrier.
    if (kt < 7) writeA(curA ^ 1);
    asm volatile("s_waitcnt lgkmcnt(0)" ::: "memory");  // A ds_writes visible
    __builtin_amdgcn_s_barrier();
    asm volatile("" ::: "memory");
  }

  // ---- epilogue: out = (acc + bias) * inv ; C layout col=lane&15, row=quad*4+reg ----
  float bn[4];
#pragma unroll
  for (int ni = 0; ni < 4; ++ni) bn[ni] = bias[n0 + wn + ni * 16 + lr];
#pragma unroll
  for (int mi = 0; mi < 4; ++mi) {
    const int gr = m0 + wm + mi * 16 + quad * 4;
#pragma unroll
    for (int ni = 0; ni < 4; ++ni) {
      const int gc = n0 + wn + ni * 16 + lr;
#pragma unroll
      for (int j = 0; j < 4; ++j)
        out[(size_t)(gr + j) * 512 + gc] = (acc[mi][ni][j] + bn[ni]) * inv;
    }
  }
}

extern "C" void kernel_launch(void* const* d_in, const int* in_sizes, int n_in,
                              void* d_out, int out_size, void* d_ws, size_t ws_size,
                              hipStream_t stream) {
  const float* x = (const float*)d_in[0];
  const float* w = (const float*)d_in[1];
  const float* bias = (const float*)d_in[2];
  float* out = (float*)d_out;

  const int K = 512, N = 512;
  const int M = in_sizes[0] / K;  // 131072

  float* ws_f = (float*)d_ws;                  // [0..16) scalars
  float* px = ws_f + 16;                       // 2048 x-partials
  float* pw = ws_f + 16 + XBLOCKS;             // 64 w-partials
  u8* wq = (u8*)((char*)d_ws + 16384);         // 256 KB fp8 quantized weight (tiled)

  hipLaunchKernelGGL(amax2_kernel, dim3(XBLOCKS + WBLOCKS), dim3(256), 0, stream,
                     (const float4*)x, (M * K) / 4, (const float4*)w, (N * K) / 4, px, pw);
  hipLaunchKernelGGL(scales_kernel, dim3(1), dim3(256), 0, stream, px, pw, ws_f);
  hipLaunchKernelGGL(quant_w_kernel, dim3((N * K / 8) / 256), dim3(256), 0, stream,
                     w, wq, ws_f);
  hipLaunchKernelGGL(gemm_kernel, dim3((M / 128) * 2), dim3(512), 0, stream,
                     x, wq, bias, out, ws_f);
}